// Round 9
// baseline (285.111 us; speedup 1.0000x reference)
//
#include <hip/hip_runtime.h>
#include <stdint.h>

#define N_ROWS 8192
#define DDIM   512

typedef __bf16 bf16_t;
typedef bf16_t bf16x8 __attribute__((ext_vector_type(8)));
typedef float  f32x4  __attribute__((ext_vector_type(4)));

#define MFMA16 __builtin_amdgcn_mfma_f32_16x16x32_bf16

// ---------------- f32 -> bf16 (RNE) convert, vectorized ----------------
__device__ inline uint16_t f2bf(float f) {
    uint32_t u = __float_as_uint(f);
    u += 0x7FFFu + ((u >> 16) & 1u);
    return (uint16_t)(u >> 16);
}

__global__ void convert_bf16(const float* __restrict__ a, const float* __restrict__ b,
                             uint16_t* __restrict__ abf, uint16_t* __restrict__ bbf) {
    const int quads = N_ROWS * DDIM / 4;
    const int stride = gridDim.x * blockDim.x;
    for (int i = blockIdx.x * blockDim.x + threadIdx.x; i < quads; i += stride) {
        float4 va = ((const float4*)a)[i];
        float4 vb = ((const float4*)b)[i];
        ushort4 ra, rb;
        ra.x = f2bf(va.x); ra.y = f2bf(va.y); ra.z = f2bf(va.z); ra.w = f2bf(va.w);
        rb.x = f2bf(vb.x); rb.y = f2bf(vb.y); rb.z = f2bf(vb.z); rb.w = f2bf(vb.w);
        ((ushort4*)abf)[i] = ra;
        ((ushort4*)bbf)[i] = rb;
    }
}

// ---------------- async global->LDS 16B stage ----------------
__device__ inline void stage16(const uint8_t* g, uint8_t* lds_wave_base) {
#if __has_builtin(__builtin_amdgcn_global_load_lds)
    __builtin_amdgcn_global_load_lds(
        (const __attribute__((address_space(1))) uint32_t*)g,
        (__attribute__((address_space(3))) uint32_t*)lds_wave_base, 16, 0, 0);
#else
    *(int4*)(lds_wave_base) = *(const int4*)g;
#endif
}

// keepalive: forces the value into registers (and the lgkm wait), emits no code
__device__ inline void keepf(const bf16x8& f) {
    const float4 v = *(const float4*)&f;
    asm volatile("" :: "v"(v.x), "v"(v.y), "v"(v.z), "v"(v.w));
}

// ============================================================================
// ABLATION ROUND (m233-style). MODE 0 = R7 kernel verbatim (real output).
// MODE 1 = no staging (global_load_lds removed -> no L2 traffic, vmcnt free).
// MODE 2 = no ds_read (constant fragments; staging+gates+MFMA kept).
// MODE 3 = no MFMA (reads kept live via keepf; epilogue on zero acc).
// Variants write only to dummy buffers; timing read from per-dispatch rocprof.
// Base structure: 256x256, BK=64, 8 waves, LDS dbuf, 1 vmcnt(0)+barrier/tile,
// reg-dbuf'd k-step fragments, XOR-swizzled LDS (0 conflicts, R5/R7-measured),
// 2D-chunked XCD swizzle (FETCH 24.7 MB, R5-measured).
// ============================================================================
template<int MODE>
__global__ void __launch_bounds__(512, 2)
clip_gemm(const uint16_t* __restrict__ A, const uint16_t* __restrict__ B,
          const float* __restrict__ scale_p,
          float* __restrict__ rowsum, float* __restrict__ colsum,
          float* __restrict__ diag) {
    __shared__ __attribute__((aligned(16))) uint8_t sh[131072];

    const int t    = threadIdx.x;
    const int wave = t >> 6;
    const int lane = t & 63;
    const int wm   = wave >> 2;    // 0..1  (M half: 128 rows)
    const int wn   = wave & 3;     // 0..3  (N slice: 64 cols)
    const int lr   = lane & 15;
    const int lg   = lane >> 4;
    const int l7   = lane & 7;

    // 2D-chunked XCD swizzle: xcd owns 8bm x 16bn, bm-fastest.
    const int orig = blockIdx.x;               // 0..1023
    const int xcd  = orig & 7;
    const int idx  = orig >> 3;                // 0..127
    const int bm   = (xcd & 3) * 8  + (idx & 7);
    const int bn   = (xcd >> 2) * 16 + (idx >> 3);

    const float s     = *scale_p;
    const float shift = s - 64.0f;

    f32x4 acc[8][4];
#pragma unroll
    for (int i = 0; i < 8; ++i)
#pragma unroll
        for (int j = 0; j < 4; ++j)
#pragma unroll
            for (int r = 0; r < 4; ++r) acc[i][j][r] = 0.0f;

    // staging source (inverse-swizzled): thread t supplies row c*64+(t>>3),
    // granule (t&7)^((t>>3)&7) of K-tile kt.
    const int g16 = (((t & 7) ^ ((t >> 3) & 7)) << 4);
    const uint8_t* srcA = (const uint8_t*)A + (size_t)(bm * 256 + (t >> 3)) * 1024 + g16;
    const uint8_t* srcB = (const uint8_t*)B + (size_t)(bn * 256 + (t >> 3)) * 1024 + g16;
    uint8_t* dA = sh + wave * 1024;
    uint8_t* dB = sh + 32768 + wave * 1024;

#define STAGE8(kt, bsel) do {                                                   \
        if constexpr (MODE != 1) {                                              \
            _Pragma("unroll")                                                   \
            for (int c = 0; c < 4; ++c) {                                       \
                stage16(srcA + (size_t)(kt) * 128 + (size_t)c * 65536,          \
                        dA + (bsel) * 65536 + c * 8192);                        \
                stage16(srcB + (size_t)(kt) * 128 + (size_t)c * 65536,          \
                        dB + (bsel) * 65536 + c * 8192);                        \
            }                                                                   \
        }                                                                       \
    } while (0)

    // fragment read offsets: chunk octet (kk*4+lg) ^ (lane&7)  [0 conflicts]
    const int x0   = ((lg) ^ l7) << 4;        // kk=0
    const int x1   = ((4 | lg) ^ l7) << 4;    // kk=1
    const int aRow = (wm * 128 + lr) * 128;
    const int bRow = 32768 + (wn * 64 + lr) * 128;

    bf16x8 aC[8], bC[4], aN[8], bN[4];
    if constexpr (MODE == 2) {
#pragma unroll
        for (int i = 0; i < 8; ++i) { aC[i] = bf16x8{}; aN[i] = bf16x8{}; }
#pragma unroll
        for (int j = 0; j < 4; ++j) { bC[j] = bf16x8{}; bN[j] = bf16x8{}; }
    }

#define LOAD12(AF, BF, BASE, X) do {                                            \
        if constexpr (MODE != 2) {                                              \
            const uint8_t* _b = (BASE);                                         \
            _Pragma("unroll")                                                   \
            for (int i = 0; i < 8; ++i)                                         \
                AF[i] = *(const bf16x8*)(_b + aRow + i * 2048 + (X));           \
            _Pragma("unroll")                                                   \
            for (int j = 0; j < 4; ++j)                                         \
                BF[j] = *(const bf16x8*)(_b + bRow + j * 2048 + (X));           \
        }                                                                       \
    } while (0)

#define MMA32(AF, BF) do {                                                      \
        if constexpr (MODE != 3) {                                              \
            __builtin_amdgcn_s_setprio(1);                                      \
            _Pragma("unroll")                                                   \
            for (int i = 0; i < 8; ++i)                                         \
                _Pragma("unroll")                                               \
                for (int j = 0; j < 4; ++j)                                     \
                    acc[i][j] = MFMA16(AF[i], BF[j], acc[i][j], 0, 0, 0);       \
            __builtin_amdgcn_s_setprio(0);                                      \
        } else {                                                                \
            _Pragma("unroll")                                                   \
            for (int i = 0; i < 8; ++i) keepf(AF[i]);                           \
            _Pragma("unroll")                                                   \
            for (int j = 0; j < 4; ++j) keepf(BF[j]);                           \
        }                                                                       \
    } while (0)

    // ---------------- prologue ----------------
    STAGE8(0, 0);
    STAGE8(1, 1);
    asm volatile("s_waitcnt vmcnt(8)" ::: "memory");   // own tile-0 loads done
    __builtin_amdgcn_s_barrier();                      // => all waves'

    LOAD12(aC, bC, sh, x0);                            // tile 0, kk=0

    // ---------------- main loop: 8 K-tiles ----------------
    for (int tt = 0; tt < 8; ++tt) {
        const uint8_t* base  = sh + (tt & 1) * 65536;
        const uint8_t* obase = sh + ((tt + 1) & 1) * 65536;

        LOAD12(aN, bN, base, x1);                      // this tile, kk=1
        MMA32(aC, bC);                                 // kk=0

        asm volatile("s_waitcnt vmcnt(0)" ::: "memory");
        __builtin_amdgcn_s_barrier();

        if (tt < 6) STAGE8(tt + 2, tt & 1);
        if (tt < 7) LOAD12(aC, bC, obase, x0);         // next tile, kk=0
        MMA32(aN, bN);                                 // kk=1
    }
#undef STAGE8
#undef LOAD12
#undef MMA32

    // ---------------- epilogue: exp + reductions ----------------
    // D layout (16x16): col = lr, row = lg*4 + r.
    float cp[4] = {0.f, 0.f, 0.f, 0.f};
#pragma unroll
    for (int i = 0; i < 8; ++i) {
        float rp[4] = {0.f, 0.f, 0.f, 0.f};
#pragma unroll
        for (int j = 0; j < 4; ++j) {
#pragma unroll
            for (int r = 0; r < 4; ++r) {
                const float logit = s * acc[i][j][r];
                const float e = __expf(logit - shift);
                rp[r] += e;
                cp[j] += e;
                if (bm == bn) {
                    const int rr = wm * 128 + i * 16 + lg * 4 + r;
                    const int cc = wn * 64 + j * 16 + lr;
                    if (rr == cc) diag[bm * 256 + rr] = logit;
                }
            }
        }
#pragma unroll
        for (int r = 0; r < 4; ++r) {
            float v = rp[r];
            v += __shfl_xor(v, 1);
            v += __shfl_xor(v, 2);
            v += __shfl_xor(v, 4);
            v += __shfl_xor(v, 8);
            if (lr == 0)
                atomicAdd(&rowsum[bm * 256 + wm * 128 + i * 16 + lg * 4 + r], v);
        }
    }
#pragma unroll
    for (int j = 0; j < 4; ++j) {
        float v = cp[j];
        v += __shfl_xor(v, 16);
        v += __shfl_xor(v, 32);
        if (lg == 0)
            atomicAdd(&colsum[bn * 256 + wn * 64 + j * 16 + lr], v);
    }
}

// ---------------- final reduce: loss scalar (parallel) ----------------
__global__ void clip_finalize(const float* __restrict__ rowsum, const float* __restrict__ colsum,
                              const float* __restrict__ diag, const float* __restrict__ scale_p,
                              float* __restrict__ out) {
    __shared__ float red[4];
    const float s = *scale_p;
    const float shift = s - 64.0f;
    const int i = blockIdx.x * 256 + threadIdx.x;   // grid 32 x 256 = 8192
    float acc = logf(rowsum[i]) + logf(colsum[i]) + 2.f * shift - 2.f * diag[i];
#pragma unroll
    for (int m = 1; m < 64; m <<= 1) acc += __shfl_xor(acc, m);
    const int wave = threadIdx.x >> 6;
    const int lane = threadIdx.x & 63;
    if (lane == 0) red[wave] = acc;
    __syncthreads();
    if (threadIdx.x == 0) {
        atomicAdd(out, (red[0] + red[1] + red[2] + red[3]) / (2.0f * N_ROWS));
    }
}

extern "C" void kernel_launch(void* const* d_in, const int* in_sizes, int n_in,
                              void* d_out, int out_size, void* d_ws, size_t ws_size,
                              hipStream_t stream) {
    const float* img     = (const float*)d_in[0];
    const float* txt     = (const float*)d_in[1];
    const float* scale_p = (const float*)d_in[2];

    uint8_t* ws = (uint8_t*)d_ws;
    uint16_t* Abf   = (uint16_t*)ws;                                  // 8 MB
    uint16_t* Bbf   = (uint16_t*)(ws + (size_t)8 * 1024 * 1024);      // 8 MB
    float*    rowsum = (float*)(ws + (size_t)16 * 1024 * 1024);       // 32 KB
    float*    colsum = rowsum + N_ROWS;                               // 32 KB
    float*    diag   = colsum + N_ROWS;                               // 32 KB
    // dummy sinks for ablation variants (never read)
    float*    drow   = (float*)(ws + (size_t)16 * 1024 * 1024 + 128 * 1024);
    float*    dcol   = drow + N_ROWS;
    float*    ddiag  = dcol + N_ROWS;
    float*    out    = (float*)d_out;

    hipMemsetAsync(rowsum, 0, 2 * N_ROWS * sizeof(float), stream);
    hipMemsetAsync(out, 0, sizeof(float), stream);
    convert_bf16<<<1024, 256, 0, stream>>>(img, txt, Abf, Bbf);
    // MODE 0: real result (R7 kernel verbatim)
    clip_gemm<0><<<1024, 512, 0, stream>>>(Abf, Bbf, scale_p, rowsum, colsum, diag);
    // Ablation variants (timing only, dummy outputs)
    clip_gemm<1><<<1024, 512, 0, stream>>>(Abf, Bbf, scale_p, drow, dcol, ddiag);
    clip_gemm<2><<<1024, 512, 0, stream>>>(Abf, Bbf, scale_p, drow, dcol, ddiag);
    clip_gemm<3><<<1024, 512, 0, stream>>>(Abf, Bbf, scale_p, drow, dcol, ddiag);
    clip_finalize<<<32, 256, 0, stream>>>(rowsum, colsum, diag, scale_p, out);
}

// Round 10
// 107.952 us; speedup vs baseline: 2.6411x; 2.6411x over previous
//
#include <hip/hip_runtime.h>
#include <stdint.h>

#define N_ROWS 8192
#define DDIM   512

typedef __bf16 bf16_t;
typedef bf16_t bf16x8 __attribute__((ext_vector_type(8)));
typedef float  f32x4  __attribute__((ext_vector_type(4)));
typedef __attribute__((address_space(3))) uint8_t lds_t;

#define MFMA16 __builtin_amdgcn_mfma_f32_16x16x32_bf16

// ---------------- f32 -> bf16 (RNE) convert, vectorized ----------------
__device__ inline uint16_t f2bf(float f) {
    uint32_t u = __float_as_uint(f);
    u += 0x7FFFu + ((u >> 16) & 1u);
    return (uint16_t)(u >> 16);
}

__global__ void convert_bf16(const float* __restrict__ a, const float* __restrict__ b,
                             uint16_t* __restrict__ abf, uint16_t* __restrict__ bbf) {
    const int quads = N_ROWS * DDIM / 4;
    const int stride = gridDim.x * blockDim.x;
    for (int i = blockIdx.x * blockDim.x + threadIdx.x; i < quads; i += stride) {
        float4 va = ((const float4*)a)[i];
        float4 vb = ((const float4*)b)[i];
        ushort4 ra, rb;
        ra.x = f2bf(va.x); ra.y = f2bf(va.y); ra.z = f2bf(va.z); ra.w = f2bf(va.w);
        rb.x = f2bf(vb.x); rb.y = f2bf(vb.y); rb.z = f2bf(vb.z); rb.w = f2bf(vb.w);
        ((ushort4*)abf)[i] = ra;
        ((ushort4*)bbf)[i] = rb;
    }
}

// ---------------- async global->LDS 16B stage ----------------
__device__ inline void stage16(const uint8_t* g, uint8_t* lds_wave_base) {
#if __has_builtin(__builtin_amdgcn_global_load_lds)
    __builtin_amdgcn_global_load_lds(
        (const __attribute__((address_space(1))) uint32_t*)g,
        (__attribute__((address_space(3))) uint32_t*)lds_wave_base, 16, 0, 0);
#else
    *(int4*)(lds_wave_base) = *(const int4*)g;
#endif
}

// ============================================================================
// R10: manual-wait pipeline. R9's ablation showed stage/ds_read/MFMA fully
// SERIALIZED (each ablation −28 µs of 88.5; 3x28 = whole kernel). Compiler-
// generated ds_reads get conservatively gated against global_load_lds (alias),
// so overlap never materializes at source level. Fix: inline-asm ds_read_b128
// with MANUAL counted waits:
//   issue 12 reads (kk=1) -> lgkmcnt(12) [kk=0 frags ready; new 12 drain
//   UNDER the 32-MFMA cluster] -> sched_barrier(0) [rule #18] -> MFMA ->
//   lgkmcnt(0) [free] -> barrier [WAR] -> STAGE8(tt+2) -> vmcnt(8) [counted,
//   never 0 until tail] -> barrier -> 12 reads next tile kk=0 -> MFMA kk=1.
// Base: 256x256, BK=64, 8 waves (2Mx4N), LDS dbuf 128 KB, XOR bank swizzle
// (0 conflicts, measured), 2D-chunked XCD swizzle (FETCH 24.7 MB, measured).
// ============================================================================
__global__ void __launch_bounds__(512, 2)
clip_gemm(const uint16_t* __restrict__ A, const uint16_t* __restrict__ B,
          const float* __restrict__ scale_p,
          float* __restrict__ rowsum, float* __restrict__ colsum,
          float* __restrict__ diag) {
    __shared__ __attribute__((aligned(16))) uint8_t sh[131072];

    const int t    = threadIdx.x;
    const int wave = t >> 6;
    const int lane = t & 63;
    const int wm   = wave >> 2;    // 0..1  (M half: 128 rows)
    const int wn   = wave & 3;     // 0..3  (N slice: 64 cols)
    const int lr   = lane & 15;
    const int lg   = lane >> 4;
    const int l7   = lane & 7;

    // 2D-chunked XCD swizzle: xcd owns 8bm x 16bn, bm-fastest.
    const int orig = blockIdx.x;               // 0..1023
    const int xcd  = orig & 7;
    const int idx  = orig >> 3;                // 0..127
    const int bm   = (xcd & 3) * 8  + (idx & 7);
    const int bn   = (xcd >> 2) * 16 + (idx >> 3);

    const float s     = *scale_p;
    const float shift = s - 64.0f;

    f32x4 acc[8][4];
#pragma unroll
    for (int i = 0; i < 8; ++i)
#pragma unroll
        for (int j = 0; j < 4; ++j)
#pragma unroll
            for (int r = 0; r < 4; ++r) acc[i][j][r] = 0.0f;

    // staging source (inverse-swizzled): thread t supplies row c*64+(t>>3),
    // granule (t&7)^((t>>3)&7) of K-tile kt.
    const int g16 = (((t & 7) ^ ((t >> 3) & 7)) << 4);
    const uint8_t* srcA = (const uint8_t*)A + (size_t)(bm * 256 + (t >> 3)) * 1024 + g16;
    const uint8_t* srcB = (const uint8_t*)B + (size_t)(bn * 256 + (t >> 3)) * 1024 + g16;
    uint8_t* dA = sh + wave * 1024;
    uint8_t* dB = sh + 32768 + wave * 1024;

#define STAGE8(kt, bsel) do {                                                   \
        _Pragma("unroll")                                                       \
        for (int c = 0; c < 4; ++c) {                                           \
            stage16(srcA + (size_t)(kt) * 128 + (size_t)c * 65536,              \
                    dA + (bsel) * 65536 + c * 8192);                            \
            stage16(srcB + (size_t)(kt) * 128 + (size_t)c * 65536,              \
                    dB + (bsel) * 65536 + c * 8192);                            \
        }                                                                       \
    } while (0)

    // fragment read offsets: chunk octet (kk*4+lg) ^ (lane&7)  [0 conflicts]
    const int x0   = ((lg) ^ l7) << 4;        // kk=0
    const int x1   = ((4 | lg) ^ l7) << 4;    // kk=1
    const int aRow = (wm * 128 + lr) * 128;
    const int bRow = 32768 + (wn * 64 + lr) * 128;

    // 32-bit LDS byte offsets for inline-asm ds_read
    const uint32_t shOff = (uint32_t)(uintptr_t)(lds_t*)sh;
    const uint32_t aX0 = shOff + (uint32_t)(aRow + x0);
    const uint32_t aX1 = shOff + (uint32_t)(aRow + x1);
    const uint32_t bX0 = shOff + (uint32_t)(bRow + x0);
    const uint32_t bX1 = shOff + (uint32_t)(bRow + x1);

#define DSR(dst, addr, off) \
    asm volatile("ds_read_b128 %0, %1 offset:%2" : "=&v"(dst) : "v"(addr), "i"(off))

    // 12 asm ds_read_b128: A i=0..7 (stride 2048), B j=0..3 (stride 2048)
#define RD12(AF, BF, AADDR, BADDR) do {                                         \
        const uint32_t _aa = (AADDR), _bb = (BADDR);                            \
        DSR(AF[0], _aa, 0);     DSR(AF[1], _aa, 2048);                          \
        DSR(AF[2], _aa, 4096);  DSR(AF[3], _aa, 6144);                          \
        DSR(AF[4], _aa, 8192);  DSR(AF[5], _aa, 10240);                         \
        DSR(AF[6], _aa, 12288); DSR(AF[7], _aa, 14336);                         \
        DSR(BF[0], _bb, 0);     DSR(BF[1], _bb, 2048);                          \
        DSR(BF[2], _bb, 4096);  DSR(BF[3], _bb, 6144);                          \
    } while (0)

#define MMA32(AF, BF) do {                                                      \
        __builtin_amdgcn_s_setprio(1);                                          \
        _Pragma("unroll")                                                       \
        for (int i = 0; i < 8; ++i)                                             \
            _Pragma("unroll")                                                   \
            for (int j = 0; j < 4; ++j)                                         \
                acc[i][j] = MFMA16(AF[i], BF[j], acc[i][j], 0, 0, 0);           \
        __builtin_amdgcn_s_setprio(0);                                          \
    } while (0)

#define WLG12() asm volatile("s_waitcnt lgkmcnt(12)" ::: "memory")
#define WLG0()  asm volatile("s_waitcnt lgkmcnt(0)"  ::: "memory")
#define WVM8()  asm volatile("s_waitcnt vmcnt(8)"    ::: "memory")
#define WVM0()  asm volatile("s_waitcnt vmcnt(0)"    ::: "memory")
#define SB0()   __builtin_amdgcn_sched_barrier(0)

    bf16x8 aC[8], bC[4], aN[8], bN[4];

    // ---------------- prologue: stage tiles 0,1; issue tile0 kk=0 reads ----
    STAGE8(0, 0);
    STAGE8(1, 1);
    WVM8();                                    // tile 0 resident (own loads)
    __builtin_amdgcn_s_barrier();              // -> all waves'
    RD12(aC, bC, aX0, bX0);                    // 12 outstanding (tile0 kk=0)

    // ---------------- main loop: 8 K-tiles ----------------
    for (int tt = 0; tt < 8; ++tt) {
        const uint32_t cb = (uint32_t)((tt & 1) << 16);        // this buffer
        const uint32_t nb = (uint32_t)(((tt + 1) & 1) << 16);  // next buffer

        RD12(aN, bN, aX1 + cb, bX1 + cb);      // tile tt kk=1 (24 outstanding)
        WLG12();                               // oldest 12 (aC/bC) ready
        SB0();                                 // rule #18: pin MFMA below wait
        MMA32(aC, bC);                         // kk=0; aN/bN drain under this
        WLG0();                                // aN/bN serviced (nearly free)
        SB0();
        __builtin_amdgcn_s_barrier();          // all waves done READING buffer

        if (tt < 6)      { STAGE8(tt + 2, tt & 1); WVM8(); }  // counted: tt+1
        else if (tt == 6) { WVM0(); }                          // tail drain
        __builtin_amdgcn_s_barrier();          // tile tt+1 resident for all

        if (tt < 7) RD12(aC, bC, aX0 + nb, bX0 + nb);  // next tile kk=0
        SB0();                                 // reads issued before MFMA
        MMA32(aN, bN);                         // kk=1
    }
#undef STAGE8
#undef RD12
#undef MMA32
#undef DSR
#undef WLG12
#undef WLG0
#undef WVM8
#undef WVM0
#undef SB0

    // ---------------- epilogue: exp + reductions ----------------
    // D layout (16x16): col = lr, row = lg*4 + r  (verified R1/R5/R7).
    float cp[4] = {0.f, 0.f, 0.f, 0.f};
#pragma unroll
    for (int i = 0; i < 8; ++i) {
        float rp[4] = {0.f, 0.f, 0.f, 0.f};
#pragma unroll
        for (int j = 0; j < 4; ++j) {
#pragma unroll
            for (int r = 0; r < 4; ++r) {
                const float logit = s * acc[i][j][r];
                const float e = __expf(logit - shift);
                rp[r] += e;
                cp[j] += e;
                if (bm == bn) {
                    const int rr = wm * 128 + i * 16 + lg * 4 + r;
                    const int cc = wn * 64 + j * 16 + lr;
                    if (rr == cc) diag[bm * 256 + rr] = logit;
                }
            }
        }
#pragma unroll
        for (int r = 0; r < 4; ++r) {
            float v = rp[r];
            v += __shfl_xor(v, 1);
            v += __shfl_xor(v, 2);
            v += __shfl_xor(v, 4);
            v += __shfl_xor(v, 8);
            if (lr == 0)
                atomicAdd(&rowsum[bm * 256 + wm * 128 + i * 16 + lg * 4 + r], v);
        }
    }
#pragma unroll
    for (int j = 0; j < 4; ++j) {
        float v = cp[j];
        v += __shfl_xor(v, 16);
        v += __shfl_xor(v, 32);
        if (lg == 0)
            atomicAdd(&colsum[bn * 256 + wn * 64 + j * 16 + lr], v);
    }
}

// ---------------- final reduce: loss scalar (parallel) ----------------
__global__ void clip_finalize(const float* __restrict__ rowsum, const float* __restrict__ colsum,
                              const float* __restrict__ diag, const float* __restrict__ scale_p,
                              float* __restrict__ out) {
    __shared__ float red[4];
    const float s = *scale_p;
    const float shift = s - 64.0f;
    const int i = blockIdx.x * 256 + threadIdx.x;   // grid 32 x 256 = 8192
    float acc = logf(rowsum[i]) + logf(colsum[i]) + 2.f * shift - 2.f * diag[i];
#pragma unroll
    for (int m = 1; m < 64; m <<= 1) acc += __shfl_xor(acc, m);
    const int wave = threadIdx.x >> 6;
    const int lane = threadIdx.x & 63;
    if (lane == 0) red[wave] = acc;
    __syncthreads();
    if (threadIdx.x == 0) {
        atomicAdd(out, (red[0] + red[1] + red[2] + red[3]) / (2.0f * N_ROWS));
    }
}

extern "C" void kernel_launch(void* const* d_in, const int* in_sizes, int n_in,
                              void* d_out, int out_size, void* d_ws, size_t ws_size,
                              hipStream_t stream) {
    const float* img     = (const float*)d_in[0];
    const float* txt     = (const float*)d_in[1];
    const float* scale_p = (const float*)d_in[2];

    uint8_t* ws = (uint8_t*)d_ws;
    uint16_t* Abf   = (uint16_t*)ws;                                  // 8 MB
    uint16_t* Bbf   = (uint16_t*)(ws + (size_t)8 * 1024 * 1024);      // 8 MB
    float*    rowsum = (float*)(ws + (size_t)16 * 1024 * 1024);       // 32 KB
    float*    colsum = rowsum + N_ROWS;                               // 32 KB
    float*    diag   = colsum + N_ROWS;                               // 32 KB
    float*    out    = (float*)d_out;

    hipMemsetAsync(rowsum, 0, 2 * N_ROWS * sizeof(float), stream);
    hipMemsetAsync(out, 0, sizeof(float), stream);
    convert_bf16<<<1024, 256, 0, stream>>>(img, txt, Abf, Bbf);
    clip_gemm<<<1024, 512, 0, stream>>>(Abf, Bbf, scale_p, rowsum, colsum, diag);
    clip_finalize<<<32, 256, 0, stream>>>(rowsum, colsum, diag, scale_p, out);
}